// Round 5
// baseline (194.465 us; speedup 1.0000x reference)
//
#include <hip/hip_runtime.h>

typedef unsigned short ushort_t;
typedef __attribute__((ext_vector_type(8))) short bf16x8;
typedef __attribute__((ext_vector_type(4))) unsigned short u16x4;
typedef __attribute__((ext_vector_type(4))) float f32x4;

__device__ __forceinline__ float bf2f(ushort_t u) {
    union { unsigned int i; float f; } v; v.i = ((unsigned int)u) << 16; return v.f;
}
__device__ __forceinline__ ushort_t f2bf(float f) {
    union { float f; unsigned int i; } v; v.f = f;
    unsigned int r = v.i + 0x7FFFu + ((v.i >> 16) & 1u);   // RNE
    return (ushort_t)(r >> 16);
}
__device__ __forceinline__ short f2bs(float f) { return (short)f2bf(f); }

// Problem constants: B=16, C=64, H=W=80, s=2, Hs=Ws=160. fp32 I/O.
#define BB 16
#define CC 64
#define HH 80
#define WW 80
#define HS 160
#define WS 160
#define HW (HH*WW)          // 6400
#define HWS (HS*WS)         // 25600

// ---------------------------------------------------------------------------
// prep_x: fused transpose (x fp32 -> xT bf16 channel-last) + low-res 12-ch
// conv directly from raw weights (rows 0-7 = offset_w, rows 8-11 = mask_w)
// ---------------------------------------------------------------------------
__global__ __launch_bounds__(256) void prep_x(const float* __restrict__ x,
                                              const float* __restrict__ offset_w,
                                              const float* __restrict__ offset_b,
                                              const float* __restrict__ mask_w,
                                              const float* __restrict__ mask_b,
                                              ushort_t* __restrict__ xT,
                                              float* __restrict__ offs) {
    __shared__ float sX[64 * 65];   // [px][c], stride 65
    int t = threadIdx.x;
    int tile = blockIdx.x;          // 0..1599
    int b = tile / 100;             // 100 tiles of 64 px per image
    int hw0 = (tile - b * 100) * 64;
    const float* xb = x + (size_t)b * CC * HW + hw0;

    // load 64px x 64ch via float4 (4 iterations)
#pragma unroll
    for (int k = 0; k < 4; ++k) {
        int idx = k * 256 + t;          // 0..1023
        int c = idx >> 4;               // 0..63
        int j4 = (idx & 15) << 2;       // 0,4,..60
        f32x4 v = *(const f32x4*)(xb + c * HW + j4);
        sX[(j4 + 0) * 65 + c] = v.x;
        sX[(j4 + 1) * 65 + c] = v.y;
        sX[(j4 + 2) * 65 + c] = v.z;
        sX[(j4 + 3) * 65 + c] = v.w;
    }
    __syncthreads();

    // transpose-store xT as bf16, ushort4 per lane (4 iterations)
#pragma unroll
    for (int k = 0; k < 4; ++k) {
        int idx = k * 256 + t;
        int px = idx >> 4;
        int c4 = (idx & 15) << 2;
        u16x4 u;
        u.x = f2bf(sX[px * 65 + c4 + 0]);
        u.y = f2bf(sX[px * 65 + c4 + 1]);
        u.z = f2bf(sX[px * 65 + c4 + 2]);
        u.w = f2bf(sX[px * 65 + c4 + 3]);
        *(u16x4*)(xT + ((size_t)(b * HW) + hw0 + px) * CC + c4) = u;
    }

    // 12-channel conv: lane=px, 4 waves x 3 channels
    int px = t & 63;
    int chunk = __builtin_amdgcn_readfirstlane(t >> 6);
    int ch0 = chunk * 3;
    const float* w0 = (ch0 + 0) < 8 ? offset_w + (ch0 + 0) * 64 : mask_w + (ch0 - 8) * 64;
    const float* w1 = (ch0 + 1) < 8 ? offset_w + (ch0 + 1) * 64 : mask_w + (ch0 - 7) * 64;
    const float* w2 = (ch0 + 2) < 8 ? offset_w + (ch0 + 2) * 64 : mask_w + (ch0 - 6) * 64;
    float a0 = (ch0 + 0) < 8 ? offset_b[ch0 + 0] : mask_b[ch0 - 8];
    float a1 = (ch0 + 1) < 8 ? offset_b[ch0 + 1] : mask_b[ch0 - 7];
    float a2 = (ch0 + 2) < 8 ? offset_b[ch0 + 2] : mask_b[ch0 - 6];
#pragma unroll 4
    for (int c = 0; c < 64; ++c) {
        float v = sX[px * 65 + c];
        a0 += v * w0[c];
        a1 += v * w1[c];
        a2 += v * w2[c];
    }
    if (ch0 + 0 >= 8) a0 = 1.0f / (1.0f + __expf(-a0));
    if (ch0 + 1 >= 8) a1 = 1.0f / (1.0f + __expf(-a1));
    if (ch0 + 2 >= 8) a2 = 1.0f / (1.0f + __expf(-a2));
    float* op = offs + (size_t)(b * HW + hw0 + px) * 12;
    op[ch0 + 0] = a0;
    op[ch0 + 1] = a1;
    op[ch0 + 2] = a2;
}

// ---------------------------------------------------------------------------
// axis taps: compose grid_sample (160-grid, zero pad) with 2x bilinear
// upsample (80-grid, edge clamp) -> 3-wide window [base, base+2], base∈[0,77].
// ---------------------------------------------------------------------------
#define ACC3(w, k, val) { float _v = (val); \
    w[0] += (k) == 0 ? _v : 0.f; w[1] += (k) == 1 ? _v : 0.f; w[2] += (k) == 2 ? _v : 0.f; }

__device__ __forceinline__ void axis_taps(float pos, int& base, float w[3]) {
    float f = floorf(pos); int u0 = (int)f; float g1 = pos - f;
    w[0] = w[1] = w[2] = 0.f;
    bool v0 = (u0 >= 0) & (u0 < 160);
    bool v1 = (u0 + 1 >= 0) & (u0 + 1 < 160);
    float cc0 = 0.f, cc1 = 0.f; int ca0 = 0, ca1 = 0;
    if (v0) { cc0 = fminf(fmaxf((float)u0 * 0.5f - 0.25f, 0.f), 79.f); ca0 = (int)floorf(cc0); }
    if (v1) { cc1 = fminf(fmaxf((float)(u0 + 1) * 0.5f - 0.25f, 0.f), 79.f); ca1 = (int)floorf(cc1); }
    int first = v0 ? ca0 : (v1 ? ca1 : 0);
    base = min(first, 77);
    if (v0) {
        float wv = cc0 - (float)ca0; int c1 = min(ca0 + 1, 79);
        int k0 = ca0 - base, k1 = c1 - base;
        ACC3(w, k0, (1.f - g1) * (1.f - wv));
        ACC3(w, k1, (1.f - g1) * wv);
    }
    if (v1) {
        float wv = cc1 - (float)ca1; int c1 = min(ca1 + 1, 79);
        int k0 = ca1 - base, k1 = c1 - base;
        ACC3(w, k0, g1 * (1.f - wv));
        ACC3(w, k1, g1 * wv);
    }
}

__device__ __forceinline__ float pick4(f32x4 v, int r) {
    float lo = (r & 1) ? v.y : v.x;
    float hi = (r & 1) ? v.w : v.z;
    return (r & 2) ? hi : lo;
}

// ---------------------------------------------------------------------------
// main: 64 output pixels per block. Phase 0: wave 0 builds taps -> LDS.
// Phase 1: R3-proven scalar loop (lane = cin, 16 serial px/wave).  [BISECT]
// Phase 2: MFMA 16x16x32 bf16: D[cout][px] = W[cout][cin]*S[cin][px]; BN+SiLU.
// ---------------------------------------------------------------------------
__global__ __launch_bounds__(256) void dysample_main(const ushort_t* __restrict__ xT,
                                                     const float* __restrict__ offs,
                                                     const float* __restrict__ conv_w,
                                                     const float* __restrict__ gamma,
                                                     const float* __restrict__ beta,
                                                     const float* __restrict__ mean,
                                                     const float* __restrict__ var,
                                                     float* __restrict__ out) {
    __shared__ f32x4 sTap4[64 * 2];              // {bits,cw0,cw1,cw2},{rw0,rw1,rw2,mk}
    __shared__ __align__(16) ushort_t S[64 * 72]; // [px][cin], stride 72
    int t = threadIdx.x;
    int lane = t & 63;
    int wave = __builtin_amdgcn_readfirstlane(t >> 6);
    int quad = lane >> 4, nrow = lane & 15;
    int b = blockIdx.y;
    int pix0 = blockIdx.x * 64;

    // A-fragments straight from fp32 conv_w (row = cout, cols = cin)
    const float* wp = conv_w + (wave * 16 + nrow) * 64 + quad * 8;
    f32x4 wa0 = *(const f32x4*)(wp);
    f32x4 wa1 = *(const f32x4*)(wp + 4);
    f32x4 wb0 = *(const f32x4*)(wp + 32);
    f32x4 wb1 = *(const f32x4*)(wp + 36);
    bf16x8 af0 = (bf16x8){f2bs(wa0.x), f2bs(wa0.y), f2bs(wa0.z), f2bs(wa0.w),
                          f2bs(wa1.x), f2bs(wa1.y), f2bs(wa1.z), f2bs(wa1.w)};
    bf16x8 af1 = (bf16x8){f2bs(wb0.x), f2bs(wb0.y), f2bs(wb0.z), f2bs(wb0.w),
                          f2bs(wb1.x), f2bs(wb1.y), f2bs(wb1.z), f2bs(wb1.w)};
    int coutD = wave * 16 + quad * 4;
    float bnAv[4], bnBv[4];
#pragma unroll
    for (int j = 0; j < 4; ++j) {
        float A = gamma[coutD + j] * rsqrtf(var[coutD + j] + 1e-5f);
        bnAv[j] = A;
        bnBv[j] = beta[coutD + j] - mean[coutD + j] * A;
    }

    // ---- phase 0: taps (wave 0, lane = px)
    if (t < 64) {
        int pix = pix0 + t;
        int ho = pix / WS, wo = pix - ho * WS;
        int h = ho >> 1, w = wo >> 1, r = ((ho & 1) << 1) | (wo & 1);
        const float* op = offs + (size_t)((b * HW) + h * WW + w) * 12;
        f32x4 o0 = *(const f32x4*)(op);
        f32x4 o1 = *(const f32x4*)(op + 4);
        f32x4 o2 = *(const f32x4*)(op + 8);
        float ox = pick4(o0, r), oy = pick4(o1, r), mk = pick4(o2, r);
        float ix = (float)wo * (160.0f / 159.0f) - 0.5f + 80.0f * ox;
        float iy = (float)ho * (160.0f / 159.0f) - 0.5f + 80.0f * oy;
        int cb, rb; float cw[3], rw[3];
        axis_taps(ix, cb, cw);
        axis_taps(iy, rb, rw);
        sTap4[t * 2 + 0] = (f32x4){__int_as_float(cb | (rb << 16)), cw[0], cw[1], cw[2]};
        sTap4[t * 2 + 1] = (f32x4){rw[0], rw[1], rw[2], mk};
    }
    __syncthreads();

    // ---- phase 1 (R3-verbatim): sample 16 px per wave, lane = input channel
    const ushort_t* xb = xT + (size_t)b * HW * CC;
#pragma unroll 2
    for (int i = 0; i < 16; ++i) {
        int px = wave * 16 + i;
        f32x4 t0 = sTap4[px * 2 + 0];       // broadcast reads
        f32x4 t1 = sTap4[px * 2 + 1];
        int bits = __float_as_int(t0.x);
        int cb = bits & 0xffff, rb = bits >> 16;
        const ushort_t* p0 = xb + (rb * WW + cb) * CC + lane;
        float acc = 0.f;
#pragma unroll
        for (int rr = 0; rr < 3; ++rr) {
            const ushort_t* pr = p0 + rr * (WW * CC);
            float v0 = bf2f(pr[0]);
            float v1 = bf2f(pr[64]);
            float v2 = bf2f(pr[128]);
            float rowa = t0.y * v0 + t0.z * v1 + t0.w * v2;
            float rwv = (rr == 0) ? t1.x : ((rr == 1) ? t1.y : t1.z);
            acc += rwv * rowa;
        }
        S[px * 72 + lane] = f2bf(acc * t1.w);
    }
    __syncthreads();

    // ---- phase 2: D[cout][px] via MFMA; wave = 16-cout tile
    f32x4 acc4[4];
#pragma unroll
    for (int n = 0; n < 4; ++n) acc4[n] = (f32x4){0.f, 0.f, 0.f, 0.f};
#pragma unroll
    for (int n = 0; n < 4; ++n) {
        const ushort_t* sp = S + (n * 16 + nrow) * 72 + quad * 8;
        bf16x8 b0 = *(const bf16x8*)(sp);        // k = 0..31
        bf16x8 b1 = *(const bf16x8*)(sp + 32);   // k = 32..63
        acc4[n] = __builtin_amdgcn_mfma_f32_16x16x32_bf16(af0, b0, acc4[n], 0, 0, 0);
        acc4[n] = __builtin_amdgcn_mfma_f32_16x16x32_bf16(af1, b1, acc4[n], 0, 0, 0);
    }

    // epilogue: BN + SiLU + store
    size_t ob = (size_t)b * CC * HWS;
#pragma unroll
    for (int n = 0; n < 4; ++n) {
        int pix = pix0 + n * 16 + nrow;
#pragma unroll
        for (int j = 0; j < 4; ++j) {
            float y = acc4[n][j] * bnAv[j] + bnBv[j];
            float s = y / (1.0f + __expf(-y));
            out[ob + (size_t)(coutD + j) * HWS + pix] = s;
        }
    }
}

// ---------------------------------------------------------------------------
extern "C" void kernel_launch(void* const* d_in, const int* in_sizes, int n_in,
                              void* d_out, int out_size, void* d_ws, size_t ws_size,
                              hipStream_t stream) {
    const float* x        = (const float*)d_in[0];
    const float* offset_w = (const float*)d_in[1];
    const float* offset_b = (const float*)d_in[2];
    const float* mask_w   = (const float*)d_in[3];
    const float* mask_b   = (const float*)d_in[4];
    const float* conv_w   = (const float*)d_in[5];
    const float* bn_gamma = (const float*)d_in[6];
    const float* bn_beta  = (const float*)d_in[7];
    const float* bn_mean  = (const float*)d_in[8];
    const float* bn_var   = (const float*)d_in[9];

    char* ws = (char*)d_ws;
    size_t off = 0;
    ushort_t* xT   = (ushort_t*)(ws + off); off += (size_t)BB * HW * CC * 2;   // 13.1 MB
    float*    offs = (float*)(ws + off);    off += (size_t)BB * HW * 12 * 4;   //  4.9 MB

    prep_x<<<BB * (HW / 64), 256, 0, stream>>>(x, offset_w, offset_b, mask_w, mask_b,
                                               xT, offs);
    dysample_main<<<dim3(HWS / 64, BB), 256, 0, stream>>>(xT, offs, conv_w,
                                                          bn_gamma, bn_beta, bn_mean,
                                                          bn_var, (float*)d_out);
}